// Round 2
// baseline (377.032 us; speedup 1.0000x reference)
//
#include <hip/hip_runtime.h>
#include <hip/hip_bf16.h>

typedef unsigned short u16;
typedef __attribute__((ext_vector_type(8))) short short8;
typedef __attribute__((ext_vector_type(4))) float f32x4;

#define B_ 4
#define S_ 2048
#define D_ 768
#define H_ 12
#define HD_ 64

__device__ __forceinline__ u16 f2bf(float f) {
  union { float f; unsigned u; } c; c.f = f;
  unsigned u = c.u;
  unsigned lsb = (u >> 16) & 1u;
  u += 0x7fffu + lsb;
  return (u16)(u >> 16);
}

// ---------------- kernel 1: convert X f32 -> bf16 (vectorized) ----------------
__global__ __launch_bounds__(256) void k_cvt_x(const float* __restrict__ x,
                                               u16* __restrict__ xb, int n4) {
  int i = blockIdx.x * 256 + threadIdx.x;
  if (i < n4) {
    float4 v = reinterpret_cast<const float4*>(x)[i];
    ushort4 o;
    o.x = f2bf(v.x); o.y = f2bf(v.y); o.z = f2bf(v.z); o.w = f2bf(v.w);
    reinterpret_cast<ushort4*>(xb)[i] = o;
  }
}

// ------- kernel 2: repack QKV weights to Bt[t][n][d] bf16 (n = h*64+e), convert Wo -------
__global__ __launch_bounds__(256) void k_repack_w(const float* __restrict__ Wq,
                                                  const float* __restrict__ Wk,
                                                  const float* __restrict__ Wv,
                                                  const float* __restrict__ Wo,
                                                  u16* __restrict__ Wt,
                                                  u16* __restrict__ Wob) {
  int idx = blockIdx.x * 256 + threadIdx.x;
  const int WSZ = D_ * D_;  // 589824
  if (idx < 3 * WSZ) {
    int t = idx / WSZ, r = idx % WSZ;
    int n = r / D_, d = r % D_;
    int h = n >> 6, e = n & 63;
    const float* W = (t == 0) ? Wq : (t == 1) ? Wk : Wv;
    Wt[idx] = f2bf(W[h * (D_ * HD_) + d * HD_ + e]);
  } else {
    int o = idx - 3 * WSZ;
    if (o < WSZ) Wob[o] = f2bf(Wo[o]);
  }
}

// ---------------- kernel 3: QKV projection GEMM (bf16 MFMA) ----------------
// A = Xb [8192 x 768], Bt = Wt[t] [768(n) x 768(d)], out -> per-head [bh][s][e] bf16
__global__ __launch_bounds__(256) void k_gemm_qkv(const u16* __restrict__ Xb,
                                                  const u16* __restrict__ Wt,
                                                  const float* __restrict__ bq,
                                                  const float* __restrict__ bk,
                                                  const float* __restrict__ bv,
                                                  u16* __restrict__ Qw,
                                                  u16* __restrict__ Kw,
                                                  u16* __restrict__ Vw) {
  const int t = blockIdx.z;
  const u16* Bmat = Wt + t * (D_ * D_);
  const float* bias = (t == 0) ? bq : (t == 1) ? bk : bv;
  u16* Out = (t == 0) ? Qw : (t == 1) ? Kw : Vw;
  const float scale = (t == 0) ? 0.125f : 1.0f;
  const int m0 = blockIdx.x * 128, n0 = blockIdx.y * 128;
  __shared__ __align__(16) u16 Al[128][40];
  __shared__ __align__(16) u16 Bl[128][40];
  const int tid = threadIdx.x;
  const int lane = tid & 63, w = tid >> 6;
  const int wm = (w >> 1) * 64, wn = (w & 1) * 64;
  const int lg = lane >> 4, lr = lane & 15;
  f32x4 acc[4][4] = {};
  for (int k0 = 0; k0 < D_; k0 += 32) {
    __syncthreads();
#pragma unroll
    for (int rep = 0; rep < 2; ++rep) {
      int item = tid + rep * 256;
      int row = item >> 2, ch = (item & 3) * 8;
      uint4 av = *reinterpret_cast<const uint4*>(&Xb[(m0 + row) * D_ + k0 + ch]);
      *reinterpret_cast<uint4*>(&Al[row][ch]) = av;
      uint4 bv2 = *reinterpret_cast<const uint4*>(&Bmat[(n0 + row) * D_ + k0 + ch]);
      *reinterpret_cast<uint4*>(&Bl[row][ch]) = bv2;
    }
    __syncthreads();
    short8 af[4], bf[4];
#pragma unroll
    for (int i = 0; i < 4; i++)
      af[i] = *reinterpret_cast<const short8*>(&Al[wm + i * 16 + lr][lg * 8]);
#pragma unroll
    for (int i = 0; i < 4; i++)
      bf[i] = *reinterpret_cast<const short8*>(&Bl[wn + i * 16 + lr][lg * 8]);
#pragma unroll
    for (int mi = 0; mi < 4; mi++)
#pragma unroll
      for (int ni = 0; ni < 4; ni++)
        acc[mi][ni] = __builtin_amdgcn_mfma_f32_16x16x32_bf16(af[mi], bf[ni], acc[mi][ni], 0, 0, 0);
  }
  // epilogue: bias + (scale for Q), scatter to [b*H+h][s][e] bf16
#pragma unroll
  for (int ni = 0; ni < 4; ni++) {
    int n = n0 + wn + ni * 16 + lr;
    float bn = bias[n];
    int h = n >> 6, e = n & 63;
#pragma unroll
    for (int mi = 0; mi < 4; mi++) {
#pragma unroll
      for (int r = 0; r < 4; r++) {
        int m = m0 + wm + mi * 16 + lg * 4 + r;
        int b = m >> 11, s = m & 2047;
        float v = (acc[mi][ni][r] + bn) * scale;
        Out[((b * H_ + h) * S_ + s) * HD_ + e] = f2bf(v);
      }
    }
  }
}

// ---------------- kernel 4: flash attention (per (b,h), Q-block 128, KV tile 64) ----------------
__global__ __launch_bounds__(256) void k_attn(const u16* __restrict__ Qw,
                                              const u16* __restrict__ Kw,
                                              const u16* __restrict__ Vw,
                                              u16* __restrict__ An) {
  const int qb = blockIdx.x;   // 0..15
  const int bh = blockIdx.y;   // 0..47
  const int b = bh / H_, h = bh % H_;
  const int tid = threadIdx.x, lane = tid & 63, w = tid >> 6;
  const int lg = lane >> 4, lr = lane & 15;
  __shared__ __align__(16) u16 Kl[64][72];
  __shared__ __align__(16) u16 Vt[64][72];   // transposed: Vt[e][kj]
  __shared__ __align__(16) u16 Pb[4][32][72];
  const u16* Qp = Qw + (bh * S_ + qb * 128 + w * 32) * HD_;
  const u16* Kp = Kw + bh * S_ * HD_;
  const u16* Vp = Vw + bh * S_ * HD_;
  // Q fragments held in registers: [qif][estep]; B-operand layout (col=qi, k=e)
  short8 qf[2][2];
#pragma unroll
  for (int qif = 0; qif < 2; qif++)
#pragma unroll
    for (int es = 0; es < 2; es++)
      qf[qif][es] = *reinterpret_cast<const short8*>(&Qp[(qif * 16 + lr) * HD_ + es * 32 + lg * 8]);
  f32x4 acc[2][4] = {};
  float mcol[2] = {-INFINITY, -INFINITY};
  float lcol[2] = {0.f, 0.f};
  float mrow[2][4];
#pragma unroll
  for (int i = 0; i < 2; i++)
#pragma unroll
    for (int r = 0; r < 4; r++) mrow[i][r] = -INFINITY;

  for (int t0 = 0; t0 < S_; t0 += 64) {
    __syncthreads();
    // stage K (row-major) and V (transposed) tiles
#pragma unroll
    for (int rep = 0; rep < 2; ++rep) {
      int item = tid + rep * 256;
      int row = item >> 3, ch = (item & 7) * 8;
      uint4 kv4 = *reinterpret_cast<const uint4*>(&Kp[(t0 + row) * HD_ + ch]);
      *reinterpret_cast<uint4*>(&Kl[row][ch]) = kv4;
      uint4 vv4 = *reinterpret_cast<const uint4*>(&Vp[(t0 + row) * HD_ + ch]);
      const u16* vp = reinterpret_cast<const u16*>(&vv4);
#pragma unroll
      for (int i = 0; i < 8; i++) Vt[ch + i][row] = vp[i];
    }
    __syncthreads();
    // scores^T: st[kjf][qif], rows kj (=kjf*16+4*lg+r), cols qi (=qif*16+lr)
    f32x4 st[4][2] = {};
#pragma unroll
    for (int es = 0; es < 2; es++) {
      short8 kf[4];
#pragma unroll
      for (int kjf = 0; kjf < 4; kjf++)
        kf[kjf] = *reinterpret_cast<const short8*>(&Kl[kjf * 16 + lr][es * 32 + lg * 8]);
#pragma unroll
      for (int kjf = 0; kjf < 4; kjf++)
#pragma unroll
        for (int qif = 0; qif < 2; qif++)
          st[kjf][qif] = __builtin_amdgcn_mfma_f32_16x16x32_bf16(kf[kjf], qf[qif][es], st[kjf][qif], 0, 0, 0);
    }
    // online softmax per column qi (lane-local row: each lane owns qi = qif*16+lr)
#pragma unroll
    for (int qif = 0; qif < 2; qif++) {
      float tmax = st[0][qif][0];
#pragma unroll
      for (int kjf = 0; kjf < 4; kjf++)
#pragma unroll
        for (int r = 0; r < 4; r++) tmax = fmaxf(tmax, st[kjf][qif][r]);
      tmax = fmaxf(tmax, __shfl_xor(tmax, 16));
      tmax = fmaxf(tmax, __shfl_xor(tmax, 32));
      float mnew = fmaxf(mcol[qif], tmax);
      float csc = __expf(mcol[qif] - mnew);
      float tsum = 0.f;
      u16 pk[4][4];
#pragma unroll
      for (int kjf = 0; kjf < 4; kjf++) {
#pragma unroll
        for (int r = 0; r < 4; r++) {
          float p = __expf(st[kjf][qif][r] - mnew);
          tsum += p;
          pk[kjf][r] = f2bf(p);
        }
      }
      tsum += __shfl_xor(tsum, 16);
      tsum += __shfl_xor(tsum, 32);
      lcol[qif] = lcol[qif] * csc + tsum;
      mcol[qif] = mnew;
      // write P (A-operand layout: row qi, k=kj) into per-wave LDS buffer
#pragma unroll
      for (int kjf = 0; kjf < 4; kjf++) {
        ushort4 pv;
        pv.x = pk[kjf][0]; pv.y = pk[kjf][1]; pv.z = pk[kjf][2]; pv.w = pk[kjf][3];
        *reinterpret_cast<ushort4*>(&Pb[w][qif * 16 + lr][kjf * 16 + lg * 4]) = pv;
      }
      // broadcast new max to D-row space and rescale accumulators
#pragma unroll
      for (int r = 0; r < 4; r++) {
        float mnb = __shfl(mnew, lg * 4 + r);
        float f = __expf(mrow[qif][r] - mnb);
        mrow[qif][r] = mnb;
#pragma unroll
        for (int ef = 0; ef < 4; ef++) acc[qif][ef][r] *= f;
      }
    }
    __syncthreads();
    // PV: A = P [32 x 64], B = V [64 x 64] via Vt
#pragma unroll
    for (int ks = 0; ks < 2; ks++) {
      short8 pa[2];
#pragma unroll
      for (int qif = 0; qif < 2; qif++)
        pa[qif] = *reinterpret_cast<const short8*>(&Pb[w][qif * 16 + lr][ks * 32 + lg * 8]);
#pragma unroll
      for (int ef = 0; ef < 4; ef++) {
        short8 vf = *reinterpret_cast<const short8*>(&Vt[ef * 16 + lr][ks * 32 + lg * 8]);
#pragma unroll
        for (int qif = 0; qif < 2; qif++)
          acc[qif][ef] = __builtin_amdgcn_mfma_f32_16x16x32_bf16(pa[qif], vf, acc[qif][ef], 0, 0, 0);
      }
    }
  }
  // epilogue: divide by l, store bf16 to [b][s][h*64+e]
  int qbase = qb * 128 + w * 32;
#pragma unroll
  for (int qif = 0; qif < 2; qif++) {
#pragma unroll
    for (int r = 0; r < 4; r++) {
      float lv = __shfl(lcol[qif], lg * 4 + r);
      float linv = 1.0f / lv;
      int s = qbase + qif * 16 + lg * 4 + r;
      u16* op = &An[(b * S_ + s) * D_ + h * HD_];
#pragma unroll
      for (int ef = 0; ef < 4; ef++) op[ef * 16 + lr] = f2bf(acc[qif][ef][r] * linv);
    }
  }
}

// ---------------- kernel 5: output projection GEMM ----------------
// A = An [8192 x 768] bf16, Bt = Wob [768(j) x 768(d)] bf16, out f32 + bo
__global__ __launch_bounds__(256) void k_gemm_out(const u16* __restrict__ An,
                                                  const u16* __restrict__ Wob,
                                                  const float* __restrict__ bo,
                                                  float* __restrict__ out) {
  const int m0 = blockIdx.x * 128, n0 = blockIdx.y * 128;
  __shared__ __align__(16) u16 Al[128][40];
  __shared__ __align__(16) u16 Bl[128][40];
  const int tid = threadIdx.x;
  const int lane = tid & 63, w = tid >> 6;
  const int wm = (w >> 1) * 64, wn = (w & 1) * 64;
  const int lg = lane >> 4, lr = lane & 15;
  f32x4 acc[4][4] = {};
  for (int k0 = 0; k0 < D_; k0 += 32) {
    __syncthreads();
#pragma unroll
    for (int rep = 0; rep < 2; ++rep) {
      int item = tid + rep * 256;
      int row = item >> 2, ch = (item & 3) * 8;
      uint4 av = *reinterpret_cast<const uint4*>(&An[(m0 + row) * D_ + k0 + ch]);
      *reinterpret_cast<uint4*>(&Al[row][ch]) = av;
      uint4 bv2 = *reinterpret_cast<const uint4*>(&Wob[(n0 + row) * D_ + k0 + ch]);
      *reinterpret_cast<uint4*>(&Bl[row][ch]) = bv2;
    }
    __syncthreads();
    short8 af[4], bf[4];
#pragma unroll
    for (int i = 0; i < 4; i++)
      af[i] = *reinterpret_cast<const short8*>(&Al[wm + i * 16 + lr][lg * 8]);
#pragma unroll
    for (int i = 0; i < 4; i++)
      bf[i] = *reinterpret_cast<const short8*>(&Bl[wn + i * 16 + lr][lg * 8]);
#pragma unroll
    for (int mi = 0; mi < 4; mi++)
#pragma unroll
      for (int ni = 0; ni < 4; ni++)
        acc[mi][ni] = __builtin_amdgcn_mfma_f32_16x16x32_bf16(af[mi], bf[ni], acc[mi][ni], 0, 0, 0);
  }
#pragma unroll
  for (int ni = 0; ni < 4; ni++) {
    int n = n0 + wn + ni * 16 + lr;
    float bn = bo[n];
#pragma unroll
    for (int mi = 0; mi < 4; mi++) {
#pragma unroll
      for (int r = 0; r < 4; r++) {
        int m = m0 + wm + mi * 16 + lg * 4 + r;
        out[m * D_ + n] = acc[mi][ni][r] + bn;
      }
    }
  }
}

extern "C" void kernel_launch(void* const* d_in, const int* in_sizes, int n_in,
                              void* d_out, int out_size, void* d_ws, size_t ws_size,
                              hipStream_t stream) {
  const float* X  = (const float*)d_in[0];
  const float* Wq = (const float*)d_in[1];
  const float* bq = (const float*)d_in[2];
  const float* Wk = (const float*)d_in[3];
  const float* bk = (const float*)d_in[4];
  const float* Wv = (const float*)d_in[5];
  const float* bv = (const float*)d_in[6];
  const float* Wo = (const float*)d_in[7];
  const float* bo = (const float*)d_in[8];
  float* out = (float*)d_out;

  char* ws = (char*)d_ws;
  // region offsets (bytes)
  u16* Xb  = (u16*)(ws + 0);          // 12,582,912
  u16* Wt  = (u16*)(ws + 12582912);   //  3,538,944
  u16* Wob = (u16*)(ws + 16121856);   //  1,179,648
  u16* Qw  = (u16*)(ws + 17301504);   // 12,582,912
  u16* Kw  = (u16*)(ws + 29884416);   // 12,582,912
  u16* Vw  = (u16*)(ws + 42467328);   // 12,582,912
  u16* An  = (u16*)(ws + 55050240);   // 12,582,912  (total 67,633,152)

  const int nx4 = (B_ * S_ * D_) / 4;  // 1,572,864
  k_cvt_x<<<dim3(nx4 / 256), dim3(256), 0, stream>>>(X, Xb, nx4);
  k_repack_w<<<dim3((4 * D_ * D_) / 256), dim3(256), 0, stream>>>(Wq, Wk, Wv, Wo, Wt, Wob);
  k_gemm_qkv<<<dim3(64, 6, 3), dim3(256), 0, stream>>>(Xb, Wt, bq, bk, bv, Qw, Kw, Vw);
  k_attn<<<dim3(16, 48), dim3(256), 0, stream>>>(Qw, Kw, Vw, An);
  k_gemm_out<<<dim3(64, 6), dim3(256), 0, stream>>>(An, Wob, bo, out);
}

// Round 4
// 316.542 us; speedup vs baseline: 1.1911x; 1.1911x over previous
//
#include <hip/hip_runtime.h>
#include <hip/hip_bf16.h>

typedef unsigned short u16;
typedef __attribute__((ext_vector_type(8))) short short8;
typedef __attribute__((ext_vector_type(4))) float f32x4;

#define B_ 4
#define S_ 2048
#define D_ 768
#define H_ 12
#define HD_ 64

__device__ __forceinline__ u16 f2bf(float f) {
  union { float f; unsigned u; } c; c.f = f;
  unsigned u = c.u;
  unsigned lsb = (u >> 16) & 1u;
  u += 0x7fffu + lsb;
  return (u16)(u >> 16);
}

// ---------------- kernel 1: convert X f32 -> bf16 (vectorized) ----------------
__global__ __launch_bounds__(256) void k_cvt_x(const float* __restrict__ x,
                                               u16* __restrict__ xb, int n4) {
  int i = blockIdx.x * 256 + threadIdx.x;
  if (i < n4) {
    float4 v = reinterpret_cast<const float4*>(x)[i];
    ushort4 o;
    o.x = f2bf(v.x); o.y = f2bf(v.y); o.z = f2bf(v.z); o.w = f2bf(v.w);
    reinterpret_cast<ushort4*>(xb)[i] = o;
  }
}

// ------- kernel 2: repack QKV weights to Bt[t][n][d] bf16 (n = h*64+e), convert Wo -------
__global__ __launch_bounds__(256) void k_repack_w(const float* __restrict__ Wq,
                                                  const float* __restrict__ Wk,
                                                  const float* __restrict__ Wv,
                                                  const float* __restrict__ Wo,
                                                  u16* __restrict__ Wt,
                                                  u16* __restrict__ Wob) {
  int idx = blockIdx.x * 256 + threadIdx.x;
  const int WSZ = D_ * D_;  // 589824
  if (idx < 3 * WSZ) {
    int t = idx / WSZ, r = idx % WSZ;
    int n = r / D_, d = r % D_;
    int h = n >> 6, e = n & 63;
    const float* W = (t == 0) ? Wq : (t == 1) ? Wk : Wv;
    Wt[idx] = f2bf(W[h * (D_ * HD_) + d * HD_ + e]);
  } else {
    int o = idx - 3 * WSZ;
    if (o < WSZ) Wob[o] = f2bf(Wo[o]);
  }
}

// ---------------- kernel 3: Q/K projection GEMM (bf16 MFMA) ----------------
// A = Xb [8192 x 768], Bt = Wt[t] [768(n) x 768(d)], out -> per-head [bh][s][e] bf16
__global__ __launch_bounds__(256) void k_gemm_qkv(const u16* __restrict__ Xb,
                                                  const u16* __restrict__ Wt,
                                                  const float* __restrict__ bq,
                                                  const float* __restrict__ bk,
                                                  u16* __restrict__ Qw,
                                                  u16* __restrict__ Kw) {
  const int t = blockIdx.z;  // 0 = Q, 1 = K
  const u16* Bmat = Wt + t * (D_ * D_);
  const float* bias = (t == 0) ? bq : bk;
  u16* Out = (t == 0) ? Qw : Kw;
  const float scale = (t == 0) ? 0.125f : 1.0f;
  const int m0 = blockIdx.x * 128, n0 = blockIdx.y * 128;
  __shared__ __align__(16) u16 Al[128][40];
  __shared__ __align__(16) u16 Bl[128][40];
  const int tid = threadIdx.x;
  const int lane = tid & 63, w = tid >> 6;
  const int wm = (w >> 1) * 64, wn = (w & 1) * 64;
  const int lg = lane >> 4, lr = lane & 15;
  f32x4 acc[4][4] = {};
  for (int k0 = 0; k0 < D_; k0 += 32) {
    __syncthreads();
#pragma unroll
    for (int rep = 0; rep < 2; ++rep) {
      int item = tid + rep * 256;
      int row = item >> 2, ch = (item & 3) * 8;
      uint4 av = *reinterpret_cast<const uint4*>(&Xb[(m0 + row) * D_ + k0 + ch]);
      *reinterpret_cast<uint4*>(&Al[row][ch]) = av;
      uint4 bv2 = *reinterpret_cast<const uint4*>(&Bmat[(n0 + row) * D_ + k0 + ch]);
      *reinterpret_cast<uint4*>(&Bl[row][ch]) = bv2;
    }
    __syncthreads();
    short8 af[4], bf[4];
#pragma unroll
    for (int i = 0; i < 4; i++)
      af[i] = *reinterpret_cast<const short8*>(&Al[wm + i * 16 + lr][lg * 8]);
#pragma unroll
    for (int i = 0; i < 4; i++)
      bf[i] = *reinterpret_cast<const short8*>(&Bl[wn + i * 16 + lr][lg * 8]);
#pragma unroll
    for (int mi = 0; mi < 4; mi++)
#pragma unroll
      for (int ni = 0; ni < 4; ni++)
        acc[mi][ni] = __builtin_amdgcn_mfma_f32_16x16x32_bf16(af[mi], bf[ni], acc[mi][ni], 0, 0, 0);
  }
  // epilogue: bias + (scale for Q), scatter to [b*H+h][s][e] bf16
#pragma unroll
  for (int ni = 0; ni < 4; ni++) {
    int n = n0 + wn + ni * 16 + lr;
    float bn = bias[n];
    int h = n >> 6, e = n & 63;
#pragma unroll
    for (int mi = 0; mi < 4; mi++) {
#pragma unroll
      for (int r = 0; r < 4; r++) {
        int m = m0 + wm + mi * 16 + lg * 4 + r;
        int b = m >> 11, s = m & 2047;
        float v = (acc[mi][ni][r] + bn) * scale;
        Out[((b * H_ + h) * S_ + s) * HD_ + e] = f2bf(v);
      }
    }
  }
}

// ---------------- kernel 3b: V projection with TRANSPOSED output [bh][e][s] ----------------
// Swapped MFMA operands: D' = W·X^T, C-layout col(lane&15)=s-dim -> coalesced stores.
__global__ __launch_bounds__(256) void k_gemm_v(const u16* __restrict__ Xb,
                                                const u16* __restrict__ Wt,
                                                const float* __restrict__ bv,
                                                u16* __restrict__ VwT) {
  const u16* Bmat = Wt + 2 * (D_ * D_);
  const int m0 = blockIdx.x * 128, n0 = blockIdx.y * 128;
  __shared__ __align__(16) u16 Al[128][40];
  __shared__ __align__(16) u16 Bl[128][40];
  const int tid = threadIdx.x;
  const int lane = tid & 63, w = tid >> 6;
  const int wm = (w >> 1) * 64, wn = (w & 1) * 64;
  const int lg = lane >> 4, lr = lane & 15;
  f32x4 acc[4][4] = {};  // acc[ni][mi]: rows = n(e), cols = m(s)
  for (int k0 = 0; k0 < D_; k0 += 32) {
    __syncthreads();
#pragma unroll
    for (int rep = 0; rep < 2; ++rep) {
      int item = tid + rep * 256;
      int row = item >> 2, ch = (item & 3) * 8;
      uint4 av = *reinterpret_cast<const uint4*>(&Xb[(m0 + row) * D_ + k0 + ch]);
      *reinterpret_cast<uint4*>(&Al[row][ch]) = av;
      uint4 bv2 = *reinterpret_cast<const uint4*>(&Bmat[(n0 + row) * D_ + k0 + ch]);
      *reinterpret_cast<uint4*>(&Bl[row][ch]) = bv2;
    }
    __syncthreads();
    short8 af[4], bf[4];
#pragma unroll
    for (int i = 0; i < 4; i++)
      af[i] = *reinterpret_cast<const short8*>(&Al[wm + i * 16 + lr][lg * 8]);
#pragma unroll
    for (int i = 0; i < 4; i++)
      bf[i] = *reinterpret_cast<const short8*>(&Bl[wn + i * 16 + lr][lg * 8]);
#pragma unroll
    for (int ni = 0; ni < 4; ni++)
#pragma unroll
      for (int mi = 0; mi < 4; mi++)
        acc[ni][mi] = __builtin_amdgcn_mfma_f32_16x16x32_bf16(bf[ni], af[mi], acc[ni][mi], 0, 0, 0);
  }
  // epilogue: D'[n_local=4*lg+r][m_local=lr]; write VwT[bh][e][s]
#pragma unroll
  for (int ni = 0; ni < 4; ni++) {
#pragma unroll
    for (int r = 0; r < 4; r++) {
      int n = n0 + wn + ni * 16 + lg * 4 + r;
      int h = n >> 6, e = n & 63;
      float bn = bv[n];
#pragma unroll
      for (int mi = 0; mi < 4; mi++) {
        int m = m0 + wm + mi * 16 + lr;
        int b = m >> 11, s = m & 2047;
        VwT[((b * H_ + h) * HD_ + e) * S_ + s] = f2bf(acc[ni][mi][r] + bn);
      }
    }
  }
}

// ---------------- kernel 4: flash attention (per (b,h), Q-block 128, KV tile 64) ----------------
// V comes pre-transposed [bh][e][s]; K/V staged with T14 async-split double-issue.
__global__ __launch_bounds__(256) void k_attn(const u16* __restrict__ Qw,
                                              const u16* __restrict__ Kw,
                                              const u16* __restrict__ VwT,
                                              u16* __restrict__ An) {
  const int qb = blockIdx.x;   // 0..15
  const int bh = blockIdx.y;   // 0..47
  const int b = bh / H_, h = bh % H_;
  const int tid = threadIdx.x, lane = tid & 63, w = tid >> 6;
  const int lg = lane >> 4, lr = lane & 15;
  __shared__ __align__(16) u16 Kl[64][72];
  __shared__ __align__(16) u16 Vt[64][72];   // Vt[e][kj]
  __shared__ __align__(16) u16 Pb[4][32][72];
  const u16* Qp = Qw + (bh * S_ + qb * 128 + w * 32) * HD_;
  const u16* Kp = Kw + bh * S_ * HD_;
  const u16* VTp = VwT + bh * HD_ * S_;
  // staging coords (same for K and V tiles)
  const int srow0 = tid >> 3, srow1 = (tid + 256) >> 3;
  const int sch = (tid & 7) * 8;
  // Q fragments in registers: [qif][estep]; B-operand layout (col=qi, k=e)
  short8 qf[2][2];
#pragma unroll
  for (int qif = 0; qif < 2; qif++)
#pragma unroll
    for (int es = 0; es < 2; es++)
      qf[qif][es] = *reinterpret_cast<const short8*>(&Qp[(qif * 16 + lr) * HD_ + es * 32 + lg * 8]);
  f32x4 acc[2][4] = {};
  float mcol[2] = {-INFINITY, -INFINITY};
  float lcol[2] = {0.f, 0.f};

  // prologue: stage tile 0
  {
    uint4 k0a = *reinterpret_cast<const uint4*>(&Kp[srow0 * HD_ + sch]);
    uint4 k0b = *reinterpret_cast<const uint4*>(&Kp[srow1 * HD_ + sch]);
    uint4 v0a = *reinterpret_cast<const uint4*>(&VTp[srow0 * S_ + sch]);
    uint4 v0b = *reinterpret_cast<const uint4*>(&VTp[srow1 * S_ + sch]);
    *reinterpret_cast<uint4*>(&Kl[srow0][sch]) = k0a;
    *reinterpret_cast<uint4*>(&Kl[srow1][sch]) = k0b;
    *reinterpret_cast<uint4*>(&Vt[srow0][sch]) = v0a;
    *reinterpret_cast<uint4*>(&Vt[srow1][sch]) = v0b;
  }
  __syncthreads();

  for (int t0 = 0; t0 < S_; t0 += 64) {
    // T14: issue next-tile global loads BEFORE compute; latency hides under MFMA+softmax
    const int tn = t0 + 64;
    uint4 kna, knb, vna, vnb;
    if (tn < S_) {
      kna = *reinterpret_cast<const uint4*>(&Kp[(tn + srow0) * HD_ + sch]);
      knb = *reinterpret_cast<const uint4*>(&Kp[(tn + srow1) * HD_ + sch]);
      vna = *reinterpret_cast<const uint4*>(&VTp[srow0 * S_ + tn + sch]);
      vnb = *reinterpret_cast<const uint4*>(&VTp[srow1 * S_ + tn + sch]);
    }
    // scores^T: st[kjf][qif], rows kj (=kjf*16+4*lg+r), cols qi (=qif*16+lr)
    f32x4 st[4][2] = {};
#pragma unroll
    for (int es = 0; es < 2; es++) {
      short8 kf[4];
#pragma unroll
      for (int kjf = 0; kjf < 4; kjf++)
        kf[kjf] = *reinterpret_cast<const short8*>(&Kl[kjf * 16 + lr][es * 32 + lg * 8]);
      __builtin_amdgcn_s_setprio(1);
#pragma unroll
      for (int kjf = 0; kjf < 4; kjf++)
#pragma unroll
        for (int qif = 0; qif < 2; qif++)
          st[kjf][qif] = __builtin_amdgcn_mfma_f32_16x16x32_bf16(kf[kjf], qf[qif][es], st[kjf][qif], 0, 0, 0);
      __builtin_amdgcn_s_setprio(0);
    }
    // online softmax per qi (lane owns qi = qif*16+lr in st-space)
#pragma unroll
    for (int qif = 0; qif < 2; qif++) {
      float tmax = st[0][qif][0];
#pragma unroll
      for (int kjf = 0; kjf < 4; kjf++)
#pragma unroll
        for (int r = 0; r < 4; r++) tmax = fmaxf(tmax, st[kjf][qif][r]);
      tmax = fmaxf(tmax, __shfl_xor(tmax, 16));
      tmax = fmaxf(tmax, __shfl_xor(tmax, 32));
      float mnew = fmaxf(mcol[qif], tmax);
      float csc = __expf(mcol[qif] - mnew);
      float tsum = 0.f;
      u16 pk[4][4];
#pragma unroll
      for (int kjf = 0; kjf < 4; kjf++) {
#pragma unroll
        for (int r = 0; r < 4; r++) {
          float p = __expf(st[kjf][qif][r] - mnew);
          tsum += p;
          pk[kjf][r] = f2bf(p);
        }
      }
      tsum += __shfl_xor(tsum, 16);
      tsum += __shfl_xor(tsum, 32);
      lcol[qif] = lcol[qif] * csc + tsum;
      mcol[qif] = mnew;
      // write P (A-operand layout: row qi, k=kj) into per-wave LDS buffer
#pragma unroll
      for (int kjf = 0; kjf < 4; kjf++) {
        ushort4 pv;
        pv.x = pk[kjf][0]; pv.y = pk[kjf][1]; pv.z = pk[kjf][2]; pv.w = pk[kjf][3];
        *reinterpret_cast<ushort4*>(&Pb[w][qif * 16 + lr][kjf * 16 + lg * 4]) = pv;
      }
      // rescale accumulators: broadcast csc into acc row space (qi = qif*16+4*lg+r)
#pragma unroll
      for (int r = 0; r < 4; r++) {
        float f = __shfl(csc, lg * 4 + r);
#pragma unroll
        for (int ef = 0; ef < 4; ef++) acc[qif][ef][r] *= f;
      }
    }
    // PV: A = P [32 x 64], B = V [64 x 64] via Vt
#pragma unroll
    for (int ks = 0; ks < 2; ks++) {
      short8 pa[2];
#pragma unroll
      for (int qif = 0; qif < 2; qif++)
        pa[qif] = *reinterpret_cast<const short8*>(&Pb[w][qif * 16 + lr][ks * 32 + lg * 8]);
      __builtin_amdgcn_s_setprio(1);
#pragma unroll
      for (int ef = 0; ef < 4; ef++) {
        short8 vf = *reinterpret_cast<const short8*>(&Vt[ef * 16 + lr][ks * 32 + lg * 8]);
#pragma unroll
        for (int qif = 0; qif < 2; qif++)
          acc[qif][ef] = __builtin_amdgcn_mfma_f32_16x16x32_bf16(pa[qif], vf, acc[qif][ef], 0, 0, 0);
      }
      __builtin_amdgcn_s_setprio(0);
    }
    __syncthreads();   // all waves done reading Kl/Vt for tile t0
    if (tn < S_) {
      *reinterpret_cast<uint4*>(&Kl[srow0][sch]) = kna;
      *reinterpret_cast<uint4*>(&Kl[srow1][sch]) = knb;
      *reinterpret_cast<uint4*>(&Vt[srow0][sch]) = vna;
      *reinterpret_cast<uint4*>(&Vt[srow1][sch]) = vnb;
    }
    __syncthreads();   // next tile ready
  }
  // epilogue: divide by l, store bf16 to [b][s][h*64+e]
  int qbase = qb * 128 + w * 32;
#pragma unroll
  for (int qif = 0; qif < 2; qif++) {
#pragma unroll
    for (int r = 0; r < 4; r++) {
      float lv = __shfl(lcol[qif], lg * 4 + r);
      float linv = 1.0f / lv;
      int s = qbase + qif * 16 + lg * 4 + r;
      u16* op = &An[(b * S_ + s) * D_ + h * HD_];
#pragma unroll
      for (int ef = 0; ef < 4; ef++) op[ef * 16 + lr] = f2bf(acc[qif][ef][r] * linv);
    }
  }
}

// ---------------- kernel 5: output projection GEMM ----------------
// A = An [8192 x 768] bf16, Bt = Wob [768(j) x 768(d)] bf16, out f32 + bo
__global__ __launch_bounds__(256) void k_gemm_out(const u16* __restrict__ An,
                                                  const u16* __restrict__ Wob,
                                                  const float* __restrict__ bo,
                                                  float* __restrict__ out) {
  const int m0 = blockIdx.x * 128, n0 = blockIdx.y * 128;
  __shared__ __align__(16) u16 Al[128][40];
  __shared__ __align__(16) u16 Bl[128][40];
  const int tid = threadIdx.x;
  const int lane = tid & 63, w = tid >> 6;
  const int wm = (w >> 1) * 64, wn = (w & 1) * 64;
  const int lg = lane >> 4, lr = lane & 15;
  f32x4 acc[4][4] = {};
  for (int k0 = 0; k0 < D_; k0 += 32) {
    __syncthreads();
#pragma unroll
    for (int rep = 0; rep < 2; ++rep) {
      int item = tid + rep * 256;
      int row = item >> 2, ch = (item & 3) * 8;
      uint4 av = *reinterpret_cast<const uint4*>(&An[(m0 + row) * D_ + k0 + ch]);
      *reinterpret_cast<uint4*>(&Al[row][ch]) = av;
      uint4 bv2 = *reinterpret_cast<const uint4*>(&Wob[(n0 + row) * D_ + k0 + ch]);
      *reinterpret_cast<uint4*>(&Bl[row][ch]) = bv2;
    }
    __syncthreads();
    short8 af[4], bf[4];
#pragma unroll
    for (int i = 0; i < 4; i++)
      af[i] = *reinterpret_cast<const short8*>(&Al[wm + i * 16 + lr][lg * 8]);
#pragma unroll
    for (int i = 0; i < 4; i++)
      bf[i] = *reinterpret_cast<const short8*>(&Bl[wn + i * 16 + lr][lg * 8]);
#pragma unroll
    for (int mi = 0; mi < 4; mi++)
#pragma unroll
      for (int ni = 0; ni < 4; ni++)
        acc[mi][ni] = __builtin_amdgcn_mfma_f32_16x16x32_bf16(af[mi], bf[ni], acc[mi][ni], 0, 0, 0);
  }
#pragma unroll
  for (int ni = 0; ni < 4; ni++) {
    int n = n0 + wn + ni * 16 + lr;
    float bn = bo[n];
#pragma unroll
    for (int mi = 0; mi < 4; mi++) {
#pragma unroll
      for (int r = 0; r < 4; r++) {
        int m = m0 + wm + mi * 16 + lg * 4 + r;
        out[m * D_ + n] = acc[mi][ni][r] + bn;
      }
    }
  }
}

extern "C" void kernel_launch(void* const* d_in, const int* in_sizes, int n_in,
                              void* d_out, int out_size, void* d_ws, size_t ws_size,
                              hipStream_t stream) {
  const float* X  = (const float*)d_in[0];
  const float* Wq = (const float*)d_in[1];
  const float* bq = (const float*)d_in[2];
  const float* Wk = (const float*)d_in[3];
  const float* bk = (const float*)d_in[4];
  const float* Wv = (const float*)d_in[5];
  const float* bv = (const float*)d_in[6];
  const float* Wo = (const float*)d_in[7];
  const float* bo = (const float*)d_in[8];
  float* out = (float*)d_out;

  char* ws = (char*)d_ws;
  u16* Xb  = (u16*)(ws + 0);          // 12,582,912
  u16* Wt  = (u16*)(ws + 12582912);   //  3,538,944
  u16* Wob = (u16*)(ws + 16121856);   //  1,179,648
  u16* Qw  = (u16*)(ws + 17301504);   // 12,582,912
  u16* Kw  = (u16*)(ws + 29884416);   // 12,582,912
  u16* VwT = (u16*)(ws + 42467328);   // 12,582,912  [bh][e][s]
  u16* An  = (u16*)(ws + 55050240);   // 12,582,912  (total 67,633,152)

  const int nx4 = (B_ * S_ * D_) / 4;  // 1,572,864
  k_cvt_x<<<dim3(nx4 / 256), dim3(256), 0, stream>>>(X, Xb, nx4);
  k_repack_w<<<dim3((4 * D_ * D_) / 256), dim3(256), 0, stream>>>(Wq, Wk, Wv, Wo, Wt, Wob);
  k_gemm_qkv<<<dim3(64, 6, 2), dim3(256), 0, stream>>>(Xb, Wt, bq, bk, Qw, Kw);
  k_gemm_v<<<dim3(64, 6), dim3(256), 0, stream>>>(Xb, Wt, bv, VwT);
  k_attn<<<dim3(16, 48), dim3(256), 0, stream>>>(Qw, Kw, VwT, An);
  k_gemm_out<<<dim3(64, 6), dim3(256), 0, stream>>>(An, Wob, bo, out);
}

// Round 5
// 296.987 us; speedup vs baseline: 1.2695x; 1.0658x over previous
//
#include <hip/hip_runtime.h>
#include <hip/hip_bf16.h>

typedef unsigned short u16;
typedef __attribute__((ext_vector_type(8))) short short8;
typedef __attribute__((ext_vector_type(4))) float f32x4;

#define B_ 4
#define S_ 2048
#define D_ 768
#define H_ 12
#define HD_ 64

__device__ __forceinline__ u16 f2bf(float f) {
  union { float f; unsigned u; } c; c.f = f;
  unsigned u = c.u;
  unsigned lsb = (u >> 16) & 1u;
  u += 0x7fffu + lsb;
  return (u16)(u >> 16);
}

// packed f32x2 -> bf16x2 (RNE), 1 instr (T12)
__device__ __forceinline__ unsigned cvt_pk(float lo, float hi) {
  unsigned r;
  asm("v_cvt_pk_bf16_f32 %0, %1, %2" : "=v"(r) : "v"(lo), "v"(hi));
  return r;
}

// ---------------- kernel 1: convert f32 -> bf16 (vectorized; used for X and Wo) ----------------
__global__ __launch_bounds__(256) void k_cvt_x(const float* __restrict__ x,
                                               u16* __restrict__ xb, int n4) {
  int i = blockIdx.x * 256 + threadIdx.x;
  if (i < n4) {
    float4 v = reinterpret_cast<const float4*>(x)[i];
    ushort4 o;
    unsigned c01 = cvt_pk(v.x, v.y), c23 = cvt_pk(v.z, v.w);
    o.x = (u16)c01; o.y = (u16)(c01 >> 16); o.z = (u16)c23; o.w = (u16)(c23 >> 16);
    reinterpret_cast<ushort4*>(xb)[i] = o;
  }
}

// ------- kernel 2: repack QKV weights to Bt[t][n][d] bf16 via LDS transpose (coalesced) -------
__global__ __launch_bounds__(256) void k_repack_qkv(const float* __restrict__ Wq,
                                                    const float* __restrict__ Wk,
                                                    const float* __restrict__ Wv,
                                                    u16* __restrict__ Wt) {
  const int h = blockIdx.x;        // 0..11
  const int d0 = blockIdx.y * 64;  // 0..704
  const int t = blockIdx.z;        // 0..2
  const float* W = (t == 0) ? Wq : (t == 1) ? Wk : Wv;
  const int tid = threadIdx.x;
  __shared__ __align__(16) u16 T[64][72];  // T[e][d_local]
  // coalesced read: W[h][d0+dl][e], consecutive tid -> consecutive e
#pragma unroll
  for (int i = 0; i < 16; i++) {
    int item = i * 256 + tid;        // 0..4095
    int dl = item >> 6, e = item & 63;
    T[e][dl] = f2bf(W[h * (D_ * HD_) + (d0 + dl) * HD_ + e]);
  }
  __syncthreads();
  // coalesced write: Wt[t][(h*64+e)*768 + d0 + dl]
#pragma unroll
  for (int i = 0; i < 4; i++) {
    int item = i * 256 + tid;        // 0..1023 (x4 u16)
    int e = item >> 4, dl4 = (item & 15) * 4;
    ushort4 o = *reinterpret_cast<const ushort4*>(&T[e][dl4]);
    *reinterpret_cast<ushort4*>(&Wt[t * (D_ * D_) + (h * 64 + e) * D_ + d0 + dl4]) = o;
  }
}

// ---------------- kernel 3: Q/K projection GEMM (bf16 MFMA, T14 prefetch) ----------------
// A = Xb [8192 x 768], Bt = Wt[t] [768(n) x 768(d)], out -> per-head [bh][s][e] bf16
// Q gets scale 0.125*log2(e) folded in (softmax runs in exp2 domain).
__global__ __launch_bounds__(256) void k_gemm_qkv(const u16* __restrict__ Xb,
                                                  const u16* __restrict__ Wt,
                                                  const float* __restrict__ bq,
                                                  const float* __restrict__ bk,
                                                  u16* __restrict__ Qw,
                                                  u16* __restrict__ Kw) {
  const int t = blockIdx.z;  // 0 = Q, 1 = K
  const u16* Bmat = Wt + t * (D_ * D_);
  const float* bias = (t == 0) ? bq : bk;
  u16* Out = (t == 0) ? Qw : Kw;
  const float scale = (t == 0) ? 0.18033688f : 1.0f;  // 0.125 * log2(e)
  const int m0 = blockIdx.x * 128, n0 = blockIdx.y * 128;
  __shared__ __align__(16) u16 Al[128][40];
  __shared__ __align__(16) u16 Bl[128][40];
  const int tid = threadIdx.x;
  const int lane = tid & 63, w = tid >> 6;
  const int wm = (w >> 1) * 64, wn = (w & 1) * 64;
  const int lg = lane >> 4, lr = lane & 15;
  const int sr0 = tid >> 2, sr1 = (tid + 256) >> 2;
  const int sc = (tid & 3) * 8;
  uint4 pa0, pa1, pb0, pb1;
  auto ld = [&](int k0) {
    pa0 = *reinterpret_cast<const uint4*>(&Xb[(m0 + sr0) * D_ + k0 + sc]);
    pa1 = *reinterpret_cast<const uint4*>(&Xb[(m0 + sr1) * D_ + k0 + sc]);
    pb0 = *reinterpret_cast<const uint4*>(&Bmat[(n0 + sr0) * D_ + k0 + sc]);
    pb1 = *reinterpret_cast<const uint4*>(&Bmat[(n0 + sr1) * D_ + k0 + sc]);
  };
  auto st_lds = [&]() {
    *reinterpret_cast<uint4*>(&Al[sr0][sc]) = pa0;
    *reinterpret_cast<uint4*>(&Al[sr1][sc]) = pa1;
    *reinterpret_cast<uint4*>(&Bl[sr0][sc]) = pb0;
    *reinterpret_cast<uint4*>(&Bl[sr1][sc]) = pb1;
  };
  f32x4 acc[4][4] = {};
  ld(0); st_lds();
  __syncthreads();
  for (int k0 = 0; k0 < D_; k0 += 32) {
    bool more = (k0 + 32) < D_;
    if (more) ld(k0 + 32);          // T14: issue early, hide under MFMA
    short8 af[4], bf[4];
#pragma unroll
    for (int i = 0; i < 4; i++)
      af[i] = *reinterpret_cast<const short8*>(&Al[wm + i * 16 + lr][lg * 8]);
#pragma unroll
    for (int i = 0; i < 4; i++)
      bf[i] = *reinterpret_cast<const short8*>(&Bl[wn + i * 16 + lr][lg * 8]);
#pragma unroll
    for (int mi = 0; mi < 4; mi++)
#pragma unroll
      for (int ni = 0; ni < 4; ni++)
        acc[mi][ni] = __builtin_amdgcn_mfma_f32_16x16x32_bf16(af[mi], bf[ni], acc[mi][ni], 0, 0, 0);
    if (more) {
      __syncthreads();
      st_lds();
      __syncthreads();
    }
  }
  // epilogue: v = acc*scale + bias*scale, cvt_pk, scatter to [b*H+h][s][e] bf16
#pragma unroll
  for (int ni = 0; ni < 4; ni++) {
    int n = n0 + wn + ni * 16 + lr;
    float bns = bias[n] * scale;
    int h = n >> 6, e = n & 63;
#pragma unroll
    for (int mi = 0; mi < 4; mi++) {
      float v0 = fmaf(acc[mi][ni][0], scale, bns);
      float v1 = fmaf(acc[mi][ni][1], scale, bns);
      float v2 = fmaf(acc[mi][ni][2], scale, bns);
      float v3 = fmaf(acc[mi][ni][3], scale, bns);
      unsigned c01 = cvt_pk(v0, v1), c23 = cvt_pk(v2, v3);
      int m = m0 + wm + mi * 16 + lg * 4;
      int b = m >> 11, s = m & 2047;
      u16* base = &Out[((b * H_ + h) * S_ + s) * HD_ + e];
      base[0]       = (u16)c01;
      base[HD_]     = (u16)(c01 >> 16);
      base[2 * HD_] = (u16)c23;
      base[3 * HD_] = (u16)(c23 >> 16);
    }
  }
}

// ---------------- kernel 3b: V projection with TRANSPOSED output [bh][e][s] ----------------
__global__ __launch_bounds__(256) void k_gemm_v(const u16* __restrict__ Xb,
                                                const u16* __restrict__ Wt,
                                                const float* __restrict__ bv,
                                                u16* __restrict__ VwT) {
  const u16* Bmat = Wt + 2 * (D_ * D_);
  const int m0 = blockIdx.x * 128, n0 = blockIdx.y * 128;
  __shared__ __align__(16) u16 Al[128][40];
  __shared__ __align__(16) u16 Bl[128][40];
  const int tid = threadIdx.x;
  const int lane = tid & 63, w = tid >> 6;
  const int wm = (w >> 1) * 64, wn = (w & 1) * 64;
  const int lg = lane >> 4, lr = lane & 15;
  const int sr0 = tid >> 2, sr1 = (tid + 256) >> 2;
  const int sc = (tid & 3) * 8;
  uint4 pa0, pa1, pb0, pb1;
  auto ld = [&](int k0) {
    pa0 = *reinterpret_cast<const uint4*>(&Xb[(m0 + sr0) * D_ + k0 + sc]);
    pa1 = *reinterpret_cast<const uint4*>(&Xb[(m0 + sr1) * D_ + k0 + sc]);
    pb0 = *reinterpret_cast<const uint4*>(&Bmat[(n0 + sr0) * D_ + k0 + sc]);
    pb1 = *reinterpret_cast<const uint4*>(&Bmat[(n0 + sr1) * D_ + k0 + sc]);
  };
  auto st_lds = [&]() {
    *reinterpret_cast<uint4*>(&Al[sr0][sc]) = pa0;
    *reinterpret_cast<uint4*>(&Al[sr1][sc]) = pa1;
    *reinterpret_cast<uint4*>(&Bl[sr0][sc]) = pb0;
    *reinterpret_cast<uint4*>(&Bl[sr1][sc]) = pb1;
  };
  f32x4 acc[4][4] = {};  // acc[ni][mi]: rows = n(e), cols = m(s)
  ld(0); st_lds();
  __syncthreads();
  for (int k0 = 0; k0 < D_; k0 += 32) {
    bool more = (k0 + 32) < D_;
    if (more) ld(k0 + 32);
    short8 af[4], bf[4];
#pragma unroll
    for (int i = 0; i < 4; i++)
      af[i] = *reinterpret_cast<const short8*>(&Al[wm + i * 16 + lr][lg * 8]);
#pragma unroll
    for (int i = 0; i < 4; i++)
      bf[i] = *reinterpret_cast<const short8*>(&Bl[wn + i * 16 + lr][lg * 8]);
#pragma unroll
    for (int ni = 0; ni < 4; ni++)
#pragma unroll
      for (int mi = 0; mi < 4; mi++)
        acc[ni][mi] = __builtin_amdgcn_mfma_f32_16x16x32_bf16(bf[ni], af[mi], acc[ni][mi], 0, 0, 0);
    if (more) {
      __syncthreads();
      st_lds();
      __syncthreads();
    }
  }
  // epilogue: D'[n_local=4*lg+r][m_local=lr]; write VwT[bh][e][s]
#pragma unroll
  for (int ni = 0; ni < 4; ni++) {
#pragma unroll
    for (int r = 0; r < 4; r++) {
      int n = n0 + wn + ni * 16 + lg * 4 + r;
      int h = n >> 6, e = n & 63;
      float bn = bv[n];
      float v0 = acc[ni][0][r] + bn, v1 = acc[ni][1][r] + bn;
      float v2 = acc[ni][2][r] + bn, v3 = acc[ni][3][r] + bn;
      unsigned c01 = cvt_pk(v0, v1), c23 = cvt_pk(v2, v3);
      int m = m0 + wm + lr;
      int b = m >> 11, s = m & 2047;
      u16* base = &VwT[((b * H_ + h) * HD_ + e) * S_ + s];
      base[0]  = (u16)c01;
      base[16] = (u16)(c01 >> 16);
      base[32] = (u16)c23;
      base[48] = (u16)(c23 >> 16);
    }
  }
}

// ---------------- kernel 4: flash attention (per (b,h), Q-block 128, KV tile 64) ----------------
// exp2 domain (Q pre-scaled by 0.125*log2e); T13 defer-max; T12 cvt_pk; T14 staging.
__global__ __launch_bounds__(256) void k_attn(const u16* __restrict__ Qw,
                                              const u16* __restrict__ Kw,
                                              const u16* __restrict__ VwT,
                                              u16* __restrict__ An) {
  const int qb = blockIdx.x;   // 0..15
  const int bh = blockIdx.y;   // 0..47
  const int b = bh / H_, h = bh % H_;
  const int tid = threadIdx.x, lane = tid & 63, w = tid >> 6;
  const int lg = lane >> 4, lr = lane & 15;
  __shared__ __align__(16) u16 Kl[64][72];
  __shared__ __align__(16) u16 Vt[64][72];   // Vt[e][kj]
  __shared__ __align__(16) u16 Pb[4][32][72];
  const u16* Qp = Qw + (bh * S_ + qb * 128 + w * 32) * HD_;
  const u16* Kp = Kw + bh * S_ * HD_;
  const u16* VTp = VwT + bh * HD_ * S_;
  const int srow0 = tid >> 3, srow1 = (tid + 256) >> 3;
  const int sch = (tid & 7) * 8;
  short8 qf[2][2];
#pragma unroll
  for (int qif = 0; qif < 2; qif++)
#pragma unroll
    for (int es = 0; es < 2; es++)
      qf[qif][es] = *reinterpret_cast<const short8*>(&Qp[(qif * 16 + lr) * HD_ + es * 32 + lg * 8]);
  f32x4 acc[2][4] = {};
  float mcol[2] = {-INFINITY, -INFINITY};
  float lcol[2] = {0.f, 0.f};

  // prologue: stage tile 0
  {
    uint4 k0a = *reinterpret_cast<const uint4*>(&Kp[srow0 * HD_ + sch]);
    uint4 k0b = *reinterpret_cast<const uint4*>(&Kp[srow1 * HD_ + sch]);
    uint4 v0a = *reinterpret_cast<const uint4*>(&VTp[srow0 * S_ + sch]);
    uint4 v0b = *reinterpret_cast<const uint4*>(&VTp[srow1 * S_ + sch]);
    *reinterpret_cast<uint4*>(&Kl[srow0][sch]) = k0a;
    *reinterpret_cast<uint4*>(&Kl[srow1][sch]) = k0b;
    *reinterpret_cast<uint4*>(&Vt[srow0][sch]) = v0a;
    *reinterpret_cast<uint4*>(&Vt[srow1][sch]) = v0b;
  }
  __syncthreads();

  for (int t0 = 0; t0 < S_; t0 += 64) {
    const int tn = t0 + 64;
    uint4 kna, knb, vna, vnb;
    if (tn < S_) {    // T14: issue next-tile loads before compute
      kna = *reinterpret_cast<const uint4*>(&Kp[(tn + srow0) * HD_ + sch]);
      knb = *reinterpret_cast<const uint4*>(&Kp[(tn + srow1) * HD_ + sch]);
      vna = *reinterpret_cast<const uint4*>(&VTp[srow0 * S_ + tn + sch]);
      vnb = *reinterpret_cast<const uint4*>(&VTp[srow1 * S_ + tn + sch]);
    }
    // scores^T (log2 units): st[kjf][qif], rows kj=kjf*16+4*lg+r, cols qi=qif*16+lr
    f32x4 st[4][2] = {};
#pragma unroll
    for (int es = 0; es < 2; es++) {
      short8 kf[4];
#pragma unroll
      for (int kjf = 0; kjf < 4; kjf++)
        kf[kjf] = *reinterpret_cast<const short8*>(&Kl[kjf * 16 + lr][es * 32 + lg * 8]);
      __builtin_amdgcn_s_setprio(1);
#pragma unroll
      for (int kjf = 0; kjf < 4; kjf++)
#pragma unroll
        for (int qif = 0; qif < 2; qif++)
          st[kjf][qif] = __builtin_amdgcn_mfma_f32_16x16x32_bf16(kf[kjf], qf[qif][es], st[kjf][qif], 0, 0, 0);
      __builtin_amdgcn_s_setprio(0);
    }
    // online softmax (exp2 domain), defer-max with THR=10 log2-units
#pragma unroll
    for (int qif = 0; qif < 2; qif++) {
      float tmax = st[0][qif][0];
#pragma unroll
      for (int kjf = 0; kjf < 4; kjf++)
#pragma unroll
        for (int r = 0; r < 4; r++) tmax = fmaxf(tmax, st[kjf][qif][r]);
      tmax = fmaxf(tmax, __shfl_xor(tmax, 16));
      tmax = fmaxf(tmax, __shfl_xor(tmax, 32));
      if (__any(tmax > mcol[qif] + 10.0f)) {
        float mnew = fmaxf(mcol[qif], tmax);
        float csc = exp2f(mcol[qif] - mnew);
        mcol[qif] = mnew;
        lcol[qif] *= csc;
#pragma unroll
        for (int r = 0; r < 4; r++) {
          float f = __shfl(csc, lg * 4 + r);
#pragma unroll
          for (int ef = 0; ef < 4; ef++) acc[qif][ef][r] *= f;
        }
      }
      float m = mcol[qif];
      float tsum = 0.f;
#pragma unroll
      for (int kjf = 0; kjf < 4; kjf++) {
        float p0 = exp2f(st[kjf][qif][0] - m);
        float p1 = exp2f(st[kjf][qif][1] - m);
        float p2 = exp2f(st[kjf][qif][2] - m);
        float p3 = exp2f(st[kjf][qif][3] - m);
        tsum += (p0 + p1) + (p2 + p3);
        uint2 pv;
        pv.x = cvt_pk(p0, p1);
        pv.y = cvt_pk(p2, p3);
        *reinterpret_cast<uint2*>(&Pb[w][qif * 16 + lr][kjf * 16 + lg * 4]) = pv;
      }
      tsum += __shfl_xor(tsum, 16);
      tsum += __shfl_xor(tsum, 32);
      lcol[qif] += tsum;
    }
    // PV: A = P [32 x 64], B = V [64 x 64] via Vt
#pragma unroll
    for (int ks = 0; ks < 2; ks++) {
      short8 pa[2];
#pragma unroll
      for (int qif = 0; qif < 2; qif++)
        pa[qif] = *reinterpret_cast<const short8*>(&Pb[w][qif * 16 + lr][ks * 32 + lg * 8]);
      __builtin_amdgcn_s_setprio(1);
#pragma unroll
      for (int ef = 0; ef < 4; ef++) {
        short8 vf = *reinterpret_cast<const short8*>(&Vt[ef * 16 + lr][ks * 32 + lg * 8]);
#pragma unroll
        for (int qif = 0; qif < 2; qif++)
          acc[qif][ef] = __builtin_amdgcn_mfma_f32_16x16x32_bf16(pa[qif], vf, acc[qif][ef], 0, 0, 0);
      }
      __builtin_amdgcn_s_setprio(0);
    }
    __syncthreads();   // all waves done reading Kl/Vt for tile t0
    if (tn < S_) {
      *reinterpret_cast<uint4*>(&Kl[srow0][sch]) = kna;
      *reinterpret_cast<uint4*>(&Kl[srow1][sch]) = knb;
      *reinterpret_cast<uint4*>(&Vt[srow0][sch]) = vna;
      *reinterpret_cast<uint4*>(&Vt[srow1][sch]) = vnb;
    }
    __syncthreads();   // next tile ready
  }
  // epilogue: divide by l, store bf16 to [b][s][h*64+e]
  int qbase = qb * 128 + w * 32;
#pragma unroll
  for (int qif = 0; qif < 2; qif++) {
#pragma unroll
    for (int r = 0; r < 4; r++) {
      float lv = __shfl(lcol[qif], lg * 4 + r);
      float linv = 1.0f / lv;
      int s = qbase + qif * 16 + lg * 4 + r;
      u16* op = &An[(b * S_ + s) * D_ + h * HD_];
      float a0 = acc[qif][0][r] * linv, a1 = acc[qif][1][r] * linv;
      float a2 = acc[qif][2][r] * linv, a3 = acc[qif][3][r] * linv;
      unsigned c01 = cvt_pk(a0, a1), c23 = cvt_pk(a2, a3);
      op[0 * 16 + lr] = (u16)c01;
      op[1 * 16 + lr] = (u16)(c01 >> 16);
      op[2 * 16 + lr] = (u16)c23;
      op[3 * 16 + lr] = (u16)(c23 >> 16);
    }
  }
}

// ---------------- kernel 5: output projection GEMM (T14 prefetch) ----------------
__global__ __launch_bounds__(256) void k_gemm_out(const u16* __restrict__ An,
                                                  const u16* __restrict__ Wob,
                                                  const float* __restrict__ bo,
                                                  float* __restrict__ out) {
  const int m0 = blockIdx.x * 128, n0 = blockIdx.y * 128;
  __shared__ __align__(16) u16 Al[128][40];
  __shared__ __align__(16) u16 Bl[128][40];
  const int tid = threadIdx.x;
  const int lane = tid & 63, w = tid >> 6;
  const int wm = (w >> 1) * 64, wn = (w & 1) * 64;
  const int lg = lane >> 4, lr = lane & 15;
  const int sr0 = tid >> 2, sr1 = (tid + 256) >> 2;
  const int sc = (tid & 3) * 8;
  uint4 pa0, pa1, pb0, pb1;
  auto ld = [&](int k0) {
    pa0 = *reinterpret_cast<const uint4*>(&An[(m0 + sr0) * D_ + k0 + sc]);
    pa1 = *reinterpret_cast<const uint4*>(&An[(m0 + sr1) * D_ + k0 + sc]);
    pb0 = *reinterpret_cast<const uint4*>(&Wob[(n0 + sr0) * D_ + k0 + sc]);
    pb1 = *reinterpret_cast<const uint4*>(&Wob[(n0 + sr1) * D_ + k0 + sc]);
  };
  auto st_lds = [&]() {
    *reinterpret_cast<uint4*>(&Al[sr0][sc]) = pa0;
    *reinterpret_cast<uint4*>(&Al[sr1][sc]) = pa1;
    *reinterpret_cast<uint4*>(&Bl[sr0][sc]) = pb0;
    *reinterpret_cast<uint4*>(&Bl[sr1][sc]) = pb1;
  };
  f32x4 acc[4][4] = {};
  ld(0); st_lds();
  __syncthreads();
  for (int k0 = 0; k0 < D_; k0 += 32) {
    bool more = (k0 + 32) < D_;
    if (more) ld(k0 + 32);
    short8 af[4], bf[4];
#pragma unroll
    for (int i = 0; i < 4; i++)
      af[i] = *reinterpret_cast<const short8*>(&Al[wm + i * 16 + lr][lg * 8]);
#pragma unroll
    for (int i = 0; i < 4; i++)
      bf[i] = *reinterpret_cast<const short8*>(&Bl[wn + i * 16 + lr][lg * 8]);
#pragma unroll
    for (int mi = 0; mi < 4; mi++)
#pragma unroll
      for (int ni = 0; ni < 4; ni++)
        acc[mi][ni] = __builtin_amdgcn_mfma_f32_16x16x32_bf16(af[mi], bf[ni], acc[mi][ni], 0, 0, 0);
    if (more) {
      __syncthreads();
      st_lds();
      __syncthreads();
    }
  }
#pragma unroll
  for (int ni = 0; ni < 4; ni++) {
    int n = n0 + wn + ni * 16 + lr;
    float bn = bo[n];
#pragma unroll
    for (int mi = 0; mi < 4; mi++) {
#pragma unroll
      for (int r = 0; r < 4; r++) {
        int m = m0 + wm + mi * 16 + lg * 4 + r;
        out[m * D_ + n] = acc[mi][ni][r] + bn;
      }
    }
  }
}

extern "C" void kernel_launch(void* const* d_in, const int* in_sizes, int n_in,
                              void* d_out, int out_size, void* d_ws, size_t ws_size,
                              hipStream_t stream) {
  const float* X  = (const float*)d_in[0];
  const float* Wq = (const float*)d_in[1];
  const float* bq = (const float*)d_in[2];
  const float* Wk = (const float*)d_in[3];
  const float* bk = (const float*)d_in[4];
  const float* Wv = (const float*)d_in[5];
  const float* bv = (const float*)d_in[6];
  const float* Wo = (const float*)d_in[7];
  const float* bo = (const float*)d_in[8];
  float* out = (float*)d_out;

  char* ws = (char*)d_ws;
  u16* Xb  = (u16*)(ws + 0);          // 12,582,912
  u16* Wt  = (u16*)(ws + 12582912);   //  3,538,944
  u16* Wob = (u16*)(ws + 16121856);   //  1,179,648
  u16* Qw  = (u16*)(ws + 17301504);   // 12,582,912
  u16* Kw  = (u16*)(ws + 29884416);   // 12,582,912
  u16* VwT = (u16*)(ws + 42467328);   // 12,582,912  [bh][e][s]
  u16* An  = (u16*)(ws + 55050240);   // 12,582,912  (total 67,633,152)

  const int nx4 = (B_ * S_ * D_) / 4;   // 1,572,864
  const int nw4 = (D_ * D_) / 4;        //   147,456
  k_cvt_x<<<dim3(nx4 / 256), dim3(256), 0, stream>>>(X, Xb, nx4);
  k_cvt_x<<<dim3(nw4 / 256), dim3(256), 0, stream>>>(Wo, Wob, nw4);
  k_repack_qkv<<<dim3(12, 12, 3), dim3(256), 0, stream>>>(Wq, Wk, Wv, Wt);
  k_gemm_qkv<<<dim3(64, 6, 2), dim3(256), 0, stream>>>(Xb, Wt, bq, bk, Qw, Kw);
  k_gemm_v<<<dim3(64, 6), dim3(256), 0, stream>>>(Xb, Wt, bv, VwT);
  k_attn<<<dim3(16, 48), dim3(256), 0, stream>>>(Qw, Kw, VwT, An);
  k_gemm_out<<<dim3(64, 6), dim3(256), 0, stream>>>(An, Wob, bo, out);
}

// Round 6
// 284.510 us; speedup vs baseline: 1.3252x; 1.0439x over previous
//
#include <hip/hip_runtime.h>
#include <hip/hip_bf16.h>

typedef unsigned short u16;
typedef __attribute__((ext_vector_type(8))) short short8;
typedef __attribute__((ext_vector_type(4))) float f32x4;

#define B_ 4
#define S_ 2048
#define D_ 768
#define H_ 12
#define HD_ 64

__device__ __forceinline__ u16 f2bf(float f) {
  union { float f; unsigned u; } c; c.f = f;
  unsigned u = c.u;
  unsigned lsb = (u >> 16) & 1u;
  u += 0x7fffu + lsb;
  return (u16)(u >> 16);
}

// packed f32x2 -> bf16x2 (RNE), 1 instr (T12)
__device__ __forceinline__ unsigned cvt_pk(float lo, float hi) {
  unsigned r;
  asm("v_cvt_pk_bf16_f32 %0, %1, %2" : "=v"(r) : "v"(lo), "v"(hi));
  return r;
}

// ---------------- kernel 1: convert f32 -> bf16 (vectorized; used for X and Wo) ----------------
__global__ __launch_bounds__(256) void k_cvt_x(const float* __restrict__ x,
                                               u16* __restrict__ xb, int n4) {
  int i = blockIdx.x * 256 + threadIdx.x;
  if (i < n4) {
    float4 v = reinterpret_cast<const float4*>(x)[i];
    ushort4 o;
    unsigned c01 = cvt_pk(v.x, v.y), c23 = cvt_pk(v.z, v.w);
    o.x = (u16)c01; o.y = (u16)(c01 >> 16); o.z = (u16)c23; o.w = (u16)(c23 >> 16);
    reinterpret_cast<ushort4*>(xb)[i] = o;
  }
}

// ------- kernel 2: repack QKV weights to Bt[t][n][d] bf16 via LDS transpose (coalesced) -------
__global__ __launch_bounds__(256) void k_repack_qkv(const float* __restrict__ Wq,
                                                    const float* __restrict__ Wk,
                                                    const float* __restrict__ Wv,
                                                    u16* __restrict__ Wt) {
  const int h = blockIdx.x;        // 0..11
  const int d0 = blockIdx.y * 64;  // 0..704
  const int t = blockIdx.z;        // 0..2
  const float* W = (t == 0) ? Wq : (t == 1) ? Wk : Wv;
  const int tid = threadIdx.x;
  __shared__ __align__(16) u16 T[64][72];  // T[e][d_local]
#pragma unroll
  for (int i = 0; i < 16; i++) {
    int item = i * 256 + tid;        // 0..4095
    int dl = item >> 6, e = item & 63;
    T[e][dl] = f2bf(W[h * (D_ * HD_) + (d0 + dl) * HD_ + e]);
  }
  __syncthreads();
#pragma unroll
  for (int i = 0; i < 4; i++) {
    int item = i * 256 + tid;        // 0..1023 (x4 u16)
    int e = item >> 4, dl4 = (item & 15) * 4;
    ushort4 o = *reinterpret_cast<const ushort4*>(&T[e][dl4]);
    *reinterpret_cast<ushort4*>(&Wt[t * (D_ * D_) + (h * 64 + e) * D_ + d0 + dl4]) = o;
  }
}

// ---------------- kernel 3: FUSED Q/K/V projection GEMM (one launch, z=0..2) ----------------
// A = Xb [8192 x 768], Bt = Wt[t] [768(n) x 768(d)].
// z=0 (Q, scale=0.125*log2e) and z=1 (K): out [bh][s][e]. z=2 (V): swapped-operand
// MFMA so output is transposed -> VwT [bh][e][s] with coalesced stores.
__global__ __launch_bounds__(256) void k_gemm_proj(const u16* __restrict__ Xb,
                                                   const u16* __restrict__ Wt,
                                                   const float* __restrict__ bq,
                                                   const float* __restrict__ bk,
                                                   const float* __restrict__ bv,
                                                   u16* __restrict__ Qw,
                                                   u16* __restrict__ Kw,
                                                   u16* __restrict__ VwT) {
  const int t = blockIdx.z;  // 0=Q, 1=K, 2=V
  const u16* Bmat = Wt + t * (D_ * D_);
  const float* bias = (t == 0) ? bq : (t == 1) ? bk : bv;
  const float scale = (t == 0) ? 0.18033688f : 1.0f;  // 0.125 * log2(e)
  const int m0 = blockIdx.x * 128, n0 = blockIdx.y * 128;
  __shared__ __align__(16) u16 Al[128][40];
  __shared__ __align__(16) u16 Bl[128][40];
  const int tid = threadIdx.x;
  const int lane = tid & 63, w = tid >> 6;
  const int wm = (w >> 1) * 64, wn = (w & 1) * 64;
  const int lg = lane >> 4, lr = lane & 15;
  const int sr0 = tid >> 2, sr1 = (tid + 256) >> 2;
  const int sc = (tid & 3) * 8;
  uint4 pa0, pa1, pb0, pb1;
  auto ld = [&](int k0) {
    pa0 = *reinterpret_cast<const uint4*>(&Xb[(m0 + sr0) * D_ + k0 + sc]);
    pa1 = *reinterpret_cast<const uint4*>(&Xb[(m0 + sr1) * D_ + k0 + sc]);
    pb0 = *reinterpret_cast<const uint4*>(&Bmat[(n0 + sr0) * D_ + k0 + sc]);
    pb1 = *reinterpret_cast<const uint4*>(&Bmat[(n0 + sr1) * D_ + k0 + sc]);
  };
  auto st_lds = [&]() {
    *reinterpret_cast<uint4*>(&Al[sr0][sc]) = pa0;
    *reinterpret_cast<uint4*>(&Al[sr1][sc]) = pa1;
    *reinterpret_cast<uint4*>(&Bl[sr0][sc]) = pb0;
    *reinterpret_cast<uint4*>(&Bl[sr1][sc]) = pb1;
  };
  f32x4 acc[4][4] = {};
  ld(0); st_lds();
  __syncthreads();
  for (int k0 = 0; k0 < D_; k0 += 32) {
    bool more = (k0 + 32) < D_;
    if (more) ld(k0 + 32);          // T14 prefetch
    short8 af[4], bf[4];
#pragma unroll
    for (int i = 0; i < 4; i++)
      af[i] = *reinterpret_cast<const short8*>(&Al[wm + i * 16 + lr][lg * 8]);
#pragma unroll
    for (int i = 0; i < 4; i++)
      bf[i] = *reinterpret_cast<const short8*>(&Bl[wn + i * 16 + lr][lg * 8]);
    if (t < 2) {
#pragma unroll
      for (int mi = 0; mi < 4; mi++)
#pragma unroll
        for (int ni = 0; ni < 4; ni++)
          acc[mi][ni] = __builtin_amdgcn_mfma_f32_16x16x32_bf16(af[mi], bf[ni], acc[mi][ni], 0, 0, 0);
    } else {
#pragma unroll
      for (int ni = 0; ni < 4; ni++)
#pragma unroll
        for (int mi = 0; mi < 4; mi++)
          acc[ni][mi] = __builtin_amdgcn_mfma_f32_16x16x32_bf16(bf[ni], af[mi], acc[ni][mi], 0, 0, 0);
    }
    if (more) {
      __syncthreads();
      st_lds();
      __syncthreads();
    }
  }
  if (t < 2) {
    u16* Out = (t == 0) ? Qw : Kw;
#pragma unroll
    for (int ni = 0; ni < 4; ni++) {
      int n = n0 + wn + ni * 16 + lr;
      float bns = bias[n] * scale;
      int h = n >> 6, e = n & 63;
#pragma unroll
      for (int mi = 0; mi < 4; mi++) {
        float v0 = fmaf(acc[mi][ni][0], scale, bns);
        float v1 = fmaf(acc[mi][ni][1], scale, bns);
        float v2 = fmaf(acc[mi][ni][2], scale, bns);
        float v3 = fmaf(acc[mi][ni][3], scale, bns);
        unsigned c01 = cvt_pk(v0, v1), c23 = cvt_pk(v2, v3);
        int m = m0 + wm + mi * 16 + lg * 4;
        int b = m >> 11, s = m & 2047;
        u16* base = &Out[((b * H_ + h) * S_ + s) * HD_ + e];
        base[0]       = (u16)c01;
        base[HD_]     = (u16)(c01 >> 16);
        base[2 * HD_] = (u16)c23;
        base[3 * HD_] = (u16)(c23 >> 16);
      }
    }
  } else {
    // D'[n_local=4*lg+r][m_local=lr]; write VwT[bh][e][s]
#pragma unroll
    for (int ni = 0; ni < 4; ni++) {
#pragma unroll
      for (int r = 0; r < 4; r++) {
        int n = n0 + wn + ni * 16 + lg * 4 + r;
        int h = n >> 6, e = n & 63;
        float bn = bias[n];
        float v0 = acc[ni][0][r] + bn, v1 = acc[ni][1][r] + bn;
        float v2 = acc[ni][2][r] + bn, v3 = acc[ni][3][r] + bn;
        unsigned c01 = cvt_pk(v0, v1), c23 = cvt_pk(v2, v3);
        int m = m0 + wm + lr;
        int b = m >> 11, s = m & 2047;
        u16* base = &VwT[((b * H_ + h) * HD_ + e) * S_ + s];
        base[0]  = (u16)c01;
        base[16] = (u16)(c01 >> 16);
        base[32] = (u16)c23;
        base[48] = (u16)(c23 >> 16);
      }
    }
  }
}

// ---------------- kernel 4: flash attention — 8 waves/block, 16 Q-rows/wave ----------------
// Q-block 128 rows; KV tile 64; exp2 domain; T13 defer-max; T12 cvt_pk; T14 staging.
__global__ __launch_bounds__(512) void k_attn(const u16* __restrict__ Qw,
                                              const u16* __restrict__ Kw,
                                              const u16* __restrict__ VwT,
                                              u16* __restrict__ An) {
  const int qb = blockIdx.x;   // 0..15
  const int bh = blockIdx.y;   // 0..47
  const int b = bh / H_, h = bh % H_;
  const int tid = threadIdx.x, lane = tid & 63, w = tid >> 6;  // w: 0..7
  const int lg = lane >> 4, lr = lane & 15;
  __shared__ __align__(16) u16 Kl[64][72];
  __shared__ __align__(16) u16 Vt[64][72];     // Vt[e][kj]
  __shared__ __align__(16) u16 Pb[8][16][72];  // per-wave P rows
  const u16* Qp = Qw + (bh * S_ + qb * 128 + w * 16) * HD_;
  const u16* Kp = Kw + bh * S_ * HD_;
  const u16* VTp = VwT + bh * HD_ * S_;
  const int srow = tid >> 3;          // 0..63
  const int sch = (tid & 7) * 8;      // 0..56
  // Q fragments (B-operand: col=qi=lr, k=e)
  short8 qf[2];
#pragma unroll
  for (int es = 0; es < 2; es++)
    qf[es] = *reinterpret_cast<const short8*>(&Qp[lr * HD_ + es * 32 + lg * 8]);
  f32x4 acc[4] = {};
  float mcol = -INFINITY;
  float lcol = 0.f;

  // prologue: stage tile 0 (1 uint4 per thread per tensor)
  {
    uint4 k0 = *reinterpret_cast<const uint4*>(&Kp[srow * HD_ + sch]);
    uint4 v0 = *reinterpret_cast<const uint4*>(&VTp[srow * S_ + sch]);
    *reinterpret_cast<uint4*>(&Kl[srow][sch]) = k0;
    *reinterpret_cast<uint4*>(&Vt[srow][sch]) = v0;
  }
  __syncthreads();

  for (int t0 = 0; t0 < S_; t0 += 64) {
    const int tn = t0 + 64;
    uint4 kn, vn;
    if (tn < S_) {    // T14: issue next-tile loads before compute
      kn = *reinterpret_cast<const uint4*>(&Kp[(tn + srow) * HD_ + sch]);
      vn = *reinterpret_cast<const uint4*>(&VTp[srow * S_ + tn + sch]);
    }
    // scores^T (log2 units): st[kjf], D rows kj=kjf*16+4*lg+r, cols qi=lr
    f32x4 st[4] = {};
#pragma unroll
    for (int es = 0; es < 2; es++) {
      short8 kf[4];
#pragma unroll
      for (int kjf = 0; kjf < 4; kjf++)
        kf[kjf] = *reinterpret_cast<const short8*>(&Kl[kjf * 16 + lr][es * 32 + lg * 8]);
      __builtin_amdgcn_s_setprio(1);
#pragma unroll
      for (int kjf = 0; kjf < 4; kjf++)
        st[kjf] = __builtin_amdgcn_mfma_f32_16x16x32_bf16(kf[kjf], qf[es], st[kjf], 0, 0, 0);
      __builtin_amdgcn_s_setprio(0);
    }
    // online softmax (exp2 domain), defer-max THR=10 log2-units
    {
      float tmax = st[0][0];
#pragma unroll
      for (int kjf = 0; kjf < 4; kjf++)
#pragma unroll
        for (int r = 0; r < 4; r++) tmax = fmaxf(tmax, st[kjf][r]);
      tmax = fmaxf(tmax, __shfl_xor(tmax, 16));
      tmax = fmaxf(tmax, __shfl_xor(tmax, 32));
      if (__any(tmax > mcol + 10.0f)) {
        float mnew = fmaxf(mcol, tmax);
        float csc = exp2f(mcol - mnew);
        mcol = mnew;
        lcol *= csc;
#pragma unroll
        for (int r = 0; r < 4; r++) {
          float f = __shfl(csc, lg * 4 + r);
#pragma unroll
          for (int ef = 0; ef < 4; ef++) acc[ef][r] *= f;
        }
      }
      float m = mcol;
      float tsum = 0.f;
#pragma unroll
      for (int kjf = 0; kjf < 4; kjf++) {
        float p0 = exp2f(st[kjf][0] - m);
        float p1 = exp2f(st[kjf][1] - m);
        float p2 = exp2f(st[kjf][2] - m);
        float p3 = exp2f(st[kjf][3] - m);
        tsum += (p0 + p1) + (p2 + p3);
        uint2 pv;
        pv.x = cvt_pk(p0, p1);
        pv.y = cvt_pk(p2, p3);
        *reinterpret_cast<uint2*>(&Pb[w][lr][kjf * 16 + lg * 4]) = pv;
      }
      tsum += __shfl_xor(tsum, 16);
      tsum += __shfl_xor(tsum, 32);
      lcol += tsum;
    }
    // PV: A = P [16 x 64], B = V [64 x 64] via Vt
#pragma unroll
    for (int ks = 0; ks < 2; ks++) {
      short8 pa = *reinterpret_cast<const short8*>(&Pb[w][lr][ks * 32 + lg * 8]);
      __builtin_amdgcn_s_setprio(1);
#pragma unroll
      for (int ef = 0; ef < 4; ef++) {
        short8 vf = *reinterpret_cast<const short8*>(&Vt[ef * 16 + lr][ks * 32 + lg * 8]);
        acc[ef] = __builtin_amdgcn_mfma_f32_16x16x32_bf16(pa, vf, acc[ef], 0, 0, 0);
      }
      __builtin_amdgcn_s_setprio(0);
    }
    __syncthreads();   // all waves done reading Kl/Vt for tile t0
    if (tn < S_) {
      *reinterpret_cast<uint4*>(&Kl[srow][sch]) = kn;
      *reinterpret_cast<uint4*>(&Vt[srow][sch]) = vn;
    }
    __syncthreads();   // next tile ready
  }
  // epilogue: divide by l, store bf16 to [b][s][h*64+e]
  int qbase = qb * 128 + w * 16;
#pragma unroll
  for (int r = 0; r < 4; r++) {
    float lv = __shfl(lcol, lg * 4 + r);
    float linv = 1.0f / lv;
    int s = qbase + lg * 4 + r;
    u16* op = &An[(b * S_ + s) * D_ + h * HD_];
    float a0 = acc[0][r] * linv, a1 = acc[1][r] * linv;
    float a2 = acc[2][r] * linv, a3 = acc[3][r] * linv;
    unsigned c01 = cvt_pk(a0, a1), c23 = cvt_pk(a2, a3);
    op[0 * 16 + lr] = (u16)c01;
    op[1 * 16 + lr] = (u16)(c01 >> 16);
    op[2 * 16 + lr] = (u16)c23;
    op[3 * 16 + lr] = (u16)(c23 >> 16);
  }
}

// ---------------- kernel 5: output projection GEMM (T14 prefetch) ----------------
__global__ __launch_bounds__(256) void k_gemm_out(const u16* __restrict__ An,
                                                  const u16* __restrict__ Wob,
                                                  const float* __restrict__ bo,
                                                  float* __restrict__ out) {
  const int m0 = blockIdx.x * 128, n0 = blockIdx.y * 128;
  __shared__ __align__(16) u16 Al[128][40];
  __shared__ __align__(16) u16 Bl[128][40];
  const int tid = threadIdx.x;
  const int lane = tid & 63, w = tid >> 6;
  const int wm = (w >> 1) * 64, wn = (w & 1) * 64;
  const int lg = lane >> 4, lr = lane & 15;
  const int sr0 = tid >> 2, sr1 = (tid + 256) >> 2;
  const int sc = (tid & 3) * 8;
  uint4 pa0, pa1, pb0, pb1;
  auto ld = [&](int k0) {
    pa0 = *reinterpret_cast<const uint4*>(&An[(m0 + sr0) * D_ + k0 + sc]);
    pa1 = *reinterpret_cast<const uint4*>(&An[(m0 + sr1) * D_ + k0 + sc]);
    pb0 = *reinterpret_cast<const uint4*>(&Wob[(n0 + sr0) * D_ + k0 + sc]);
    pb1 = *reinterpret_cast<const uint4*>(&Wob[(n0 + sr1) * D_ + k0 + sc]);
  };
  auto st_lds = [&]() {
    *reinterpret_cast<uint4*>(&Al[sr0][sc]) = pa0;
    *reinterpret_cast<uint4*>(&Al[sr1][sc]) = pa1;
    *reinterpret_cast<uint4*>(&Bl[sr0][sc]) = pb0;
    *reinterpret_cast<uint4*>(&Bl[sr1][sc]) = pb1;
  };
  f32x4 acc[4][4] = {};
  ld(0); st_lds();
  __syncthreads();
  for (int k0 = 0; k0 < D_; k0 += 32) {
    bool more = (k0 + 32) < D_;
    if (more) ld(k0 + 32);
    short8 af[4], bf[4];
#pragma unroll
    for (int i = 0; i < 4; i++)
      af[i] = *reinterpret_cast<const short8*>(&Al[wm + i * 16 + lr][lg * 8]);
#pragma unroll
    for (int i = 0; i < 4; i++)
      bf[i] = *reinterpret_cast<const short8*>(&Bl[wn + i * 16 + lr][lg * 8]);
#pragma unroll
    for (int mi = 0; mi < 4; mi++)
#pragma unroll
      for (int ni = 0; ni < 4; ni++)
        acc[mi][ni] = __builtin_amdgcn_mfma_f32_16x16x32_bf16(af[mi], bf[ni], acc[mi][ni], 0, 0, 0);
    if (more) {
      __syncthreads();
      st_lds();
      __syncthreads();
    }
  }
#pragma unroll
  for (int ni = 0; ni < 4; ni++) {
    int n = n0 + wn + ni * 16 + lr;
    float bn = bo[n];
#pragma unroll
    for (int mi = 0; mi < 4; mi++) {
#pragma unroll
      for (int r = 0; r < 4; r++) {
        int m = m0 + wm + mi * 16 + lg * 4 + r;
        out[m * D_ + n] = acc[mi][ni][r] + bn;
      }
    }
  }
}

extern "C" void kernel_launch(void* const* d_in, const int* in_sizes, int n_in,
                              void* d_out, int out_size, void* d_ws, size_t ws_size,
                              hipStream_t stream) {
  const float* X  = (const float*)d_in[0];
  const float* Wq = (const float*)d_in[1];
  const float* bq = (const float*)d_in[2];
  const float* Wk = (const float*)d_in[3];
  const float* bk = (const float*)d_in[4];
  const float* Wv = (const float*)d_in[5];
  const float* bv = (const float*)d_in[6];
  const float* Wo = (const float*)d_in[7];
  const float* bo = (const float*)d_in[8];
  float* out = (float*)d_out;

  char* ws = (char*)d_ws;
  u16* Xb  = (u16*)(ws + 0);          // 12,582,912
  u16* Wt  = (u16*)(ws + 12582912);   //  3,538,944
  u16* Wob = (u16*)(ws + 16121856);   //  1,179,648
  u16* Qw  = (u16*)(ws + 17301504);   // 12,582,912
  u16* Kw  = (u16*)(ws + 29884416);   // 12,582,912
  u16* VwT = (u16*)(ws + 42467328);   // 12,582,912  [bh][e][s]
  u16* An  = (u16*)(ws + 55050240);   // 12,582,912  (total 67,633,152)

  const int nx4 = (B_ * S_ * D_) / 4;   // 1,572,864
  const int nw4 = (D_ * D_) / 4;        //   147,456
  k_cvt_x<<<dim3(nx4 / 256), dim3(256), 0, stream>>>(X, Xb, nx4);
  k_cvt_x<<<dim3(nw4 / 256), dim3(256), 0, stream>>>(Wo, Wob, nw4);
  k_repack_qkv<<<dim3(12, 12, 3), dim3(256), 0, stream>>>(Wq, Wk, Wv, Wt);
  k_gemm_proj<<<dim3(64, 6, 3), dim3(256), 0, stream>>>(Xb, Wt, bq, bk, bv, Qw, Kw, VwT);
  k_attn<<<dim3(16, 48), dim3(512), 0, stream>>>(Qw, Kw, VwT, An);
  k_gemm_out<<<dim3(64, 6), dim3(256), 0, stream>>>(An, Wob, bo, out);
}